// Round 1
// baseline (624.657 us; speedup 1.0000x reference)
//
#include <hip/hip_runtime.h>

#define NN 50000
#define EE 600000
#define HH 128
#define EDD 16
#define BB 256
#define LL 5
#define NN16 (NN * 16)
#define NSHADOW 8

typedef float f32x4 __attribute__((ext_vector_type(4)));
typedef _Float16 f16x4 __attribute__((ext_vector_type(4)));
typedef _Float16 f16x8 __attribute__((ext_vector_type(8)));

// ---------------- Weight prep: W[mat][k][n] fp32 -> frag-ordered fp16 hi/lo ----------------
__global__ __launch_bounds__(256) void wprep_k(const float* __restrict__ W,
    _Float16* __restrict__ Wh, _Float16* __restrict__ Wl, int total)
{
    int idx = blockIdx.x * 256 + threadIdx.x;
    if (idx >= total) return;
    int mat = idx >> 14;
    int r = idx & 16383;
    int j = r & 7, lane = (r >> 3) & 63, ks = (r >> 9) & 3, ntw = (r >> 11) & 7;
    int lm = lane & 15, quad = lane >> 4;
    int n = (ntw >> 1) * 32 + (ntw & 1) * 16 + lm;
    int k = ks * 32 + quad * 8 + j;
    float w = W[(mat << 14) + (k << 7) + n];
    _Float16 h = (_Float16)w;
    Wh[idx] = h;
    Wl[idx] = (_Float16)(w - (float)h);
}

// ---------------- x -> fp16 (one-time) ----------------
__global__ __launch_bounds__(256) void xprep_k(const float* __restrict__ x,
    _Float16* __restrict__ X)
{
    int i = blockIdx.x * 256 + threadIdx.x;
    if (i >= NN * 32) return;
    float4 v = ((const float4*)x)[i];
    f16x4 o;
    o[0] = (_Float16)v.x; o[1] = (_Float16)v.y; o[2] = (_Float16)v.z; o[3] = (_Float16)v.w;
    ((f16x4*)X)[i] = o;
}

// ---------------- shared GEMM helpers ----------------
__device__ __forceinline__ void stage_A16(const _Float16* __restrict__ Ag, int M, int brow,
    int tid, _Float16* __restrict__ As)
{
    const int r = tid >> 2, cg = tid & 3;
    const int grow = brow + r;
    _Float16* p = As + r * 136 + cg * 32;
    if (grow < M) {
        const f16x8* s = (const f16x8*)(Ag + (size_t)grow * 128 + cg * 32);
#pragma unroll
        for (int i = 0; i < 4; ++i) ((f16x8*)p)[i] = s[i];
    } else {
        f16x8 z = (f16x8)(_Float16)0;
#pragma unroll
        for (int i = 0; i < 4; ++i) ((f16x8*)p)[i] = z;
    }
}

__device__ __forceinline__ void mfma_stage16(
    const _Float16* __restrict__ As,
    const _Float16* __restrict__ Wh, const _Float16* __restrict__ Wl,
    int wn, int lm, int quad, int lane, f32x4 acc[4][2])
{
    f16x8 Bh[2][4], Bl[2][4];
#pragma unroll
    for (int nt = 0; nt < 2; ++nt)
#pragma unroll
        for (int ks = 0; ks < 4; ++ks) {
            int fi = ((((wn * 2 + nt) * 4) + ks) * 64 + lane) * 8;
            Bh[nt][ks] = *(const f16x8*)(Wh + fi);
            Bl[nt][ks] = *(const f16x8*)(Wl + fi);
        }
#pragma unroll
    for (int ks = 0; ks < 4; ++ks) {
        f16x8 a[4];
#pragma unroll
        for (int mt = 0; mt < 4; ++mt) {
            int off = (mt * 16 + lm) * 136 + ks * 32 + quad * 8;
            a[mt] = *(const f16x8*)(As + off);
        }
#pragma unroll
        for (int mt = 0; mt < 4; ++mt)
#pragma unroll
            for (int nt = 0; nt < 2; ++nt) {
                acc[mt][nt] = __builtin_amdgcn_mfma_f32_16x16x32_f16(a[mt], Bh[nt][ks], acc[mt][nt], 0, 0, 0);
                acc[mt][nt] = __builtin_amdgcn_mfma_f32_16x16x32_f16(a[mt], Bl[nt][ks], acc[mt][nt], 0, 0, 0);
            }
    }
}

__device__ __forceinline__ void store_f16(const _Float16* __restrict__ Fo,
    _Float16* __restrict__ out, int M, int brow, int tid)
{
    const int r = tid >> 2, cg = tid & 3;
    const int grow = brow + r;
    if (grow >= M) return;
    const f16x8* src = (const f16x8*)(Fo + r * 136 + cg * 32);
    f16x8* dst = (f16x8*)(out + (size_t)grow * 128 + cg * 32);
#pragma unroll
    for (int i = 0; i < 4; ++i) dst[i] = src[i];
}

// ---------------- fused 3-GEMM layer kernel ----------------
// X_next = relu(relu((AggX@nW + Extra) @ m1W + b1) @ m2W + b2), plus pooled partials.
// Extra = VnSum + aggE@eW + deg*(eb+nb), precomputed by aggregate2_k (linearity of segment_sum).
__global__ __launch_bounds__(256) void gemm_fused_k(
    const _Float16* __restrict__ AggX, const _Float16* __restrict__ Extra,
    const _Float16* __restrict__ WNh, const _Float16* __restrict__ WNl,
    const _Float16* __restrict__ W1h, const _Float16* __restrict__ W1l, const float* __restrict__ b1,
    const _Float16* __restrict__ W2h, const _Float16* __restrict__ W2l, const float* __restrict__ b2,
    _Float16* __restrict__ X, float* __restrict__ pooled8,
    const int* __restrict__ batch, int M)
{
    __shared__ __align__(16) _Float16 bufA[64 * 136];
    __shared__ __align__(16) _Float16 bufB[64 * 136];
    const int tid = threadIdx.x, brow = blockIdx.x * 64;

    stage_A16(AggX, M, brow, tid, bufA);
    stage_A16(Extra, M, brow, tid, bufB);
    __syncthreads();

    const int lane = tid & 63, wn = tid >> 6, lm = lane & 15, quad = lane >> 4;
    const int colb = wn * 32 + lm;

    f32x4 acc[4][2];
#pragma unroll
    for (int mt = 0; mt < 4; ++mt) { acc[mt][0] = (f32x4)(0.f); acc[mt][1] = (f32x4)(0.f); }
    mfma_stage16(bufA, WNh, WNl, wn, lm, quad, lane, acc);

    // epilogue 1 (no relu): agg_msg = AggX@nW + Extra -> bufB (each cell owned by exactly one thread)
#pragma unroll
    for (int mt = 0; mt < 4; ++mt) {
#pragma unroll
        for (int r = 0; r < 4; ++r) {
            int trow = mt * 16 + quad * 4 + r;
            _Float16* p0 = &bufB[trow * 136 + colb];
            _Float16* p1 = &bufB[trow * 136 + colb + 16];
            *p0 = (_Float16)(acc[mt][0][r] + (float)*p0);
            *p1 = (_Float16)(acc[mt][1][r] + (float)*p1);
        }
    }
    __syncthreads();

#pragma unroll
    for (int mt = 0; mt < 4; ++mt) { acc[mt][0] = (f32x4)(0.f); acc[mt][1] = (f32x4)(0.f); }
    mfma_stage16(bufB, W1h, W1l, wn, lm, quad, lane, acc);
    {
        const float c0 = b1[colb], c1 = b1[colb + 16];
#pragma unroll
        for (int mt = 0; mt < 4; ++mt) {
#pragma unroll
            for (int r = 0; r < 4; ++r) {
                int trow = mt * 16 + quad * 4 + r;
                bufA[trow * 136 + colb]      = (_Float16)fmaxf(acc[mt][0][r] + c0, 0.f);
                bufA[trow * 136 + colb + 16] = (_Float16)fmaxf(acc[mt][1][r] + c1, 0.f);
            }
        }
    }
    __syncthreads();

#pragma unroll
    for (int mt = 0; mt < 4; ++mt) { acc[mt][0] = (f32x4)(0.f); acc[mt][1] = (f32x4)(0.f); }
    mfma_stage16(bufA, W2h, W2l, wn, lm, quad, lane, acc);
    {
        const float d0 = b2[colb], d1 = b2[colb + 16];
#pragma unroll
        for (int mt = 0; mt < 4; ++mt) {
#pragma unroll
            for (int r = 0; r < 4; ++r) {
                int trow = mt * 16 + quad * 4 + r;
                bufB[trow * 136 + colb]      = (_Float16)fmaxf(acc[mt][0][r] + d0, 0.f);
                bufB[trow * 136 + colb + 16] = (_Float16)fmaxf(acc[mt][1][r] + d1, 0.f);
            }
        }
    }
    __syncthreads();
    store_f16(bufB, X, M, brow, tid);

    // pooled partial sums into shadow copy (blockIdx&7) to cut atomic line-contention 8x
    {
        float* pooled = pooled8 + (size_t)(blockIdx.x & (NSHADOW - 1)) * (BB * HH);
        const int c = tid & 127, half = tid >> 7;
        const int row0 = half * 32;
        float sum = 0.f;
        int curg = -1;
        for (int r2 = 0; r2 < 32; ++r2) {
            int grow = brow + row0 + r2;
            if (grow >= M) break;
            int g = batch[grow];
            if (g != curg) {
                if (curg >= 0) atomicAdd(&pooled[curg * 128 + c], sum);
                curg = g; sum = 0.f;
            }
            sum += (float)bufB[(row0 + r2) * 136 + c];
        }
        if (curg >= 0) atomicAdd(&pooled[curg * 128 + c], sum);
    }
}

// ---------------- Edge aggregation on raw X (linearity): AggX = sum X[src], Extra = VnSum + aggE@eW + deg*(eb+nb) ----------------
// 16 lanes/node x f16x8 (16B/lane): 4 rows in flight per wave -> 2x MLP vs 32-lane/f16x4.
__global__ __launch_bounds__(256) void aggregate2_k(
    const _Float16* __restrict__ X, const float* __restrict__ aggE,
    const float* __restrict__ eW, const float* __restrict__ eb, const float* __restrict__ nb,
    const _Float16* __restrict__ vn16, int usevn,
    const int* __restrict__ rowstart, const int4* __restrict__ csr,
    _Float16* __restrict__ AggX, _Float16* __restrict__ Extra, int n)
{
    __shared__ float eWs[16 * 128];
    __shared__ float cbs[128];   // eb + nb
    const int tid = threadIdx.x;
#pragma unroll
    for (int t = 0; t < 2; ++t) {
        int li = (tid + t * 256) * 4;
        *(float4*)(&eWs[li]) = *(const float4*)(eW + li);
    }
    if (tid < 32) {
        float4 e4 = *(const float4*)(eb + tid * 4);
        float4 n4 = *(const float4*)(nb + tid * 4);
        e4.x += n4.x; e4.y += n4.y; e4.z += n4.z; e4.w += n4.w;
        *(float4*)(&cbs[tid * 4]) = e4;
    }
    __syncthreads();

    const int lane = tid & 15;
    const int node = blockIdx.x * 16 + (tid >> 4);
    if (node >= n) return;
    const int s = rowstart[node], e = rowstart[node + 1];
    const f16x8* X8 = (const f16x8*)X;
    const f16x8* V8 = (const f16x8*)vn16;

    float ax[8], ev[8];
#pragma unroll
    for (int k = 0; k < 8; ++k) { ax[k] = 0.f; ev[k] = 0.f; }

    int p = s;
    for (; p + 4 <= e; p += 4) {
        int4 c0 = csr[p], c1 = csr[p + 1], c2 = csr[p + 2], c3 = csr[p + 3];
        f16x8 x0 = X8[(size_t)c0.x * 16 + lane];
        f16x8 x1 = X8[(size_t)c1.x * 16 + lane];
        f16x8 x2 = X8[(size_t)c2.x * 16 + lane];
        f16x8 x3 = X8[(size_t)c3.x * 16 + lane];
#pragma unroll
        for (int k = 0; k < 8; ++k)
            ax[k] += ((float)x0[k] + (float)x1[k]) + ((float)x2[k] + (float)x3[k]);
        if (usevn) {
            f16x8 v0 = V8[c0.z * 16 + lane];
            f16x8 v1 = V8[c1.z * 16 + lane];
            f16x8 v2 = V8[c2.z * 16 + lane];
            f16x8 v3 = V8[c3.z * 16 + lane];
#pragma unroll
            for (int k = 0; k < 8; ++k)
                ev[k] += ((float)v0[k] + (float)v1[k]) + ((float)v2[k] + (float)v3[k]);
        }
    }
    for (; p < e; ++p) {
        int4 c0 = csr[p];
        f16x8 x0 = X8[(size_t)c0.x * 16 + lane];
#pragma unroll
        for (int k = 0; k < 8; ++k) ax[k] += (float)x0[k];
        if (usevn) {
            f16x8 v0 = V8[c0.z * 16 + lane];
#pragma unroll
            for (int k = 0; k < 8; ++k) ev[k] += (float)v0[k];
        }
    }

    // Extra = VnSum + deg*(eb+nb) + aggE@eW
    const float degf = (float)(e - s);
    const float* ae = aggE + (size_t)node * 16;
    float et[8];
#pragma unroll
    for (int k = 0; k < 8; ++k) et[k] = ev[k] + degf * cbs[lane * 8 + k];
#pragma unroll
    for (int k = 0; k < 16; ++k) {
        float a = ae[k];
        float4 wa = *(const float4*)(&eWs[k * 128 + lane * 8]);
        float4 wb = *(const float4*)(&eWs[k * 128 + lane * 8 + 4]);
        et[0] = fmaf(a, wa.x, et[0]); et[1] = fmaf(a, wa.y, et[1]);
        et[2] = fmaf(a, wa.z, et[2]); et[3] = fmaf(a, wa.w, et[3]);
        et[4] = fmaf(a, wb.x, et[4]); et[5] = fmaf(a, wb.y, et[5]);
        et[6] = fmaf(a, wb.z, et[6]); et[7] = fmaf(a, wb.w, et[7]);
    }

    f16x8 ox, oe;
#pragma unroll
    for (int k = 0; k < 8; ++k) { ox[k] = (_Float16)ax[k]; oe[k] = (_Float16)et[k]; }
    ((f16x8*)AggX)[(size_t)node * 16 + lane] = ox;
    ((f16x8*)Extra)[(size_t)node * 16 + lane] = oe;
}

// ---------------- aggE[n,16] = sum of eattr over in-edges ----------------
__global__ __launch_bounds__(256) void aggE_k(
    const float* __restrict__ eattr, const int* __restrict__ rowstart,
    const int4* __restrict__ csr, float* __restrict__ aggE, int n)
{
    const int lane = threadIdx.x & 15;
    const int node = blockIdx.x * 16 + (threadIdx.x >> 4);
    if (node >= n) return;
    const int s = rowstart[node], e = rowstart[node + 1];
    float acc = 0.f;
    for (int p = s; p < e; ++p)
        acc += eattr[(size_t)csr[p].y * 16 + lane];
    aggE[(size_t)node * 16 + lane] = acc;
}

// ---------------- VN update from shadowed pooled sums (also clears them; emits fp16 copy) ----------------
__global__ __launch_bounds__(128) void vn_update_k(
    float* __restrict__ pooled8, const int* __restrict__ gstart,
    const float* __restrict__ W0, const float* __restrict__ b0,
    const float* __restrict__ W1, const float* __restrict__ b1,
    float* __restrict__ vn, _Float16* __restrict__ vn16)
{
    __shared__ float p[128], q[128];
    const int g = blockIdx.x, t = threadIdx.x;
    float cnt = (float)(gstart[g + 1] - gstart[g]);
    if (cnt < 1.f) cnt = 1.f;
    float sum = 0.f;
#pragma unroll
    for (int s = 0; s < NSHADOW; ++s) {
        float* slot = pooled8 + (size_t)s * (BB * HH) + g * 128 + t;
        sum += *slot;
        *slot = 0.f;
    }
    p[t] = sum / cnt;
    __syncthreads();
    float a0 = b0[t];
    for (int k = 0; k < 128; ++k) a0 = fmaf(p[k], W0[k * 128 + t], a0);
    q[t] = fmaxf(a0, 0.f);
    __syncthreads();
    float a1 = b1[t];
    for (int k = 0; k < 128; ++k) a1 = fmaf(q[k], W1[k * 128 + t], a1);
    float nv = vn[g * 128 + t] + fmaxf(a1, 0.f);
    vn[g * 128 + t] = nv;
    vn16[g * 128 + t] = (_Float16)nv;
}

// ---------------- final classifier from shadowed pooled sums ----------------
__global__ __launch_bounds__(128) void fc_k(
    const float* __restrict__ pooled8, const int* __restrict__ gstart,
    const float* __restrict__ W, const float* __restrict__ b,
    float* __restrict__ out)
{
    __shared__ float p[128];
    const int g = blockIdx.x, t = threadIdx.x;
    float cnt = (float)(gstart[g + 1] - gstart[g]);
    if (cnt < 1.f) cnt = 1.f;
    float sum = 0.f;
#pragma unroll
    for (int s = 0; s < NSHADOW; ++s)
        sum += pooled8[(size_t)s * (BB * HH) + g * 128 + t];
    p[t] = sum / cnt;
    __syncthreads();
    float acc = b[t];
    for (int k = 0; k < 128; ++k) acc = fmaf(p[k], W[k * 128 + t], acc);
    out[g * 128 + t] = acc;
}

// ---------------- CSR build helpers ----------------
__global__ void histp_k(const int* __restrict__ idx, int n, int* __restrict__ cntp)
{
    int i = blockIdx.x * 256 + threadIdx.x;
    if (i < n) atomicAdd(&cntp[(blockIdx.x & 3) * NN16 + (idx[i] << 4)], 1);
}

__global__ void scan_deg_k(const int* __restrict__ degp, int n, int* __restrict__ out, int* __restrict__ bsum)
{
    __shared__ int s[256];
    int gid = blockIdx.x * 256 + threadIdx.x;
    int v = 0;
    if (gid < n) {
        int o = gid << 4;
        v = degp[o] + degp[NN16 + o] + degp[2 * NN16 + o] + degp[3 * NN16 + o];
    }
    s[threadIdx.x] = v;
    __syncthreads();
    for (int off = 1; off < 256; off <<= 1) {
        int t = (threadIdx.x >= off) ? s[threadIdx.x - off] : 0;
        __syncthreads();
        s[threadIdx.x] += t;
        __syncthreads();
    }
    int incl = s[threadIdx.x];
    if (gid < n) out[gid] = incl - v;
    if (bsum != nullptr && threadIdx.x == 255) bsum[blockIdx.x] = incl;
}

__global__ void scan_k(const int* __restrict__ in, int n, int* __restrict__ out, int* __restrict__ bsum)
{
    __shared__ int s[256];
    int gid = blockIdx.x * 256 + threadIdx.x;
    int v = (gid < n) ? in[gid] : 0;
    s[threadIdx.x] = v;
    __syncthreads();
    for (int off = 1; off < 256; off <<= 1) {
        int t = (threadIdx.x >= off) ? s[threadIdx.x - off] : 0;
        __syncthreads();
        s[threadIdx.x] += t;
        __syncthreads();
    }
    int incl = s[threadIdx.x];
    if (gid < n) out[gid] = incl - v;
    if (bsum != nullptr && threadIdx.x == 255) bsum[blockIdx.x] = incl;
}

__global__ void addoff_k(int* __restrict__ data, const int* __restrict__ boff, int n, int total)
{
    int i = blockIdx.x * 256 + threadIdx.x;
    if (i < n) data[i] += boff[blockIdx.x];
    if (i == 0) data[n] = total;
}

__global__ void curinit_k(const int* __restrict__ rowstart, int* __restrict__ cursorp)
{
    int i = blockIdx.x * 256 + threadIdx.x;
    if (i < NN) cursorp[i << 4] = rowstart[i];
}

__global__ void fill_k(const int* __restrict__ dst, const int* __restrict__ src, int n,
                       const int* __restrict__ batch,
                       int* __restrict__ cursorp, int4* __restrict__ csr)
{
    int e = blockIdx.x * 256 + threadIdx.x;
    if (e < n) {
        int sv = src[e];
        int slot = atomicAdd(&cursorp[dst[e] << 4], 1);
        int4 pr; pr.x = sv; pr.y = e; pr.z = batch[sv]; pr.w = 0;
        csr[slot] = pr;
    }
}

__global__ void gstart_k(const int* __restrict__ batch, int* __restrict__ gstart)
{
    int b = blockIdx.x * 64 + threadIdx.x;
    if (b > BB) return;
    if (b == BB) { gstart[BB] = NN; return; }
    int lo = 0, hi = NN;
    while (lo < hi) {
        int mid = (lo + hi) >> 1;
        if (batch[mid] < b) lo = mid + 1; else hi = mid;
    }
    gstart[b] = lo;
}

__global__ void vninit_k(const float* __restrict__ vninit, float* __restrict__ vn,
                         _Float16* __restrict__ vn16, float* __restrict__ pooled8)
{
    int i = blockIdx.x * 256 + threadIdx.x;
    if (i < BB * HH) {
        float v = vninit[i & 127];
        vn[i] = v;
        vn16[i] = (_Float16)v;
    }
    if (i < NSHADOW * BB * HH) pooled8[i] = 0.f;
}

// ---------------- Launch ----------------
extern "C" void kernel_launch(void* const* d_in, const int* in_sizes, int n_in,
                              void* d_out, int out_size, void* d_ws, size_t ws_size,
                              hipStream_t stream)
{
    (void)in_sizes; (void)n_in; (void)out_size; (void)ws_size;
    const float* x       = (const float*)d_in[0];
    const float* eattr   = (const float*)d_in[1];
    const float* node_W  = (const float*)d_in[2];
    const float* node_b  = (const float*)d_in[3];
    const float* edge_W  = (const float*)d_in[4];
    const float* edge_b  = (const float*)d_in[5];
    const float* mlp1_W  = (const float*)d_in[6];
    const float* mlp1_b  = (const float*)d_in[7];
    const float* mlp2_W  = (const float*)d_in[8];
    const float* mlp2_b  = (const float*)d_in[9];
    const float* vn_w0   = (const float*)d_in[10];
    const float* vn_b0   = (const float*)d_in[11];
    const float* vn_w1   = (const float*)d_in[12];
    const float* vn_b1   = (const float*)d_in[13];
    const float* fc_W    = (const float*)d_in[14];
    const float* fc_b    = (const float*)d_in[15];
    const float* vn_init = (const float*)d_in[16];
    const int*   eidx    = (const int*)d_in[17];
    const int*   batch   = (const int*)d_in[18];
    const int* srcv = eidx;
    const int* dstv = eidx + EE;

    char* wp = (char*)d_ws;
    auto alloc = [&](size_t bytes) -> void* {
        void* p = (void*)wp;
        wp += (bytes + 255) & ~(size_t)255;
        return p;
    };
    _Float16* X0   = (_Float16*)alloc((size_t)NN * HH * 2);
    _Float16* X    = (_Float16*)alloc((size_t)NN * HH * 2);
    _Float16* AggX = (_Float16*)alloc((size_t)NN * HH * 2);
    _Float16* Extra= (_Float16*)alloc((size_t)NN * HH * 2);
    float* aggE    = (float*)alloc((size_t)NN * EDD * 4);
    float* vn      = (float*)alloc((size_t)BB * HH * 4);
    _Float16* vn16 = (_Float16*)alloc((size_t)BB * HH * 2);
    float* pooled8 = (float*)alloc((size_t)NSHADOW * BB * HH * 4);
    int* degp      = (int*)alloc((size_t)4 * NN16 * 4);
    int* rowstart  = (int*)alloc((size_t)(NN + 1) * 4);
    int* cursorp   = (int*)alloc((size_t)NN16 * 4);
    int4* csr      = (int4*)alloc((size_t)EE * 16);
    int* bsum      = (int*)alloc(256 * 4);
    int* boff      = (int*)alloc(256 * 4);
    int* gstart    = (int*)alloc((size_t)(BB + 1) * 4);
    _Float16* WtN_h = (_Float16*)alloc((size_t)5 * 16384 * 2);
    _Float16* WtN_l = (_Float16*)alloc((size_t)5 * 16384 * 2);
    _Float16* Wt1_h = (_Float16*)alloc((size_t)5 * 16384 * 2);
    _Float16* Wt1_l = (_Float16*)alloc((size_t)5 * 16384 * 2);
    _Float16* Wt2_h = (_Float16*)alloc((size_t)5 * 16384 * 2);
    _Float16* Wt2_l = (_Float16*)alloc((size_t)5 * 16384 * 2);

    hipMemsetAsync(degp, 0, (size_t)4 * NN16 * 4, stream);

    histp_k<<<(EE + 255) / 256, 256, 0, stream>>>(dstv, EE, degp);

    const int NB1 = (NN + 255) / 256;
    scan_deg_k<<<NB1, 256, 0, stream>>>(degp, NN, rowstart, bsum);
    scan_k<<<1, 256, 0, stream>>>(bsum, NB1, boff, nullptr);
    addoff_k<<<NB1, 256, 0, stream>>>(rowstart, boff, NN, EE);
    curinit_k<<<NB1, 256, 0, stream>>>(rowstart, cursorp);
    fill_k<<<(EE + 255) / 256, 256, 0, stream>>>(dstv, srcv, EE, batch, cursorp, csr);

    gstart_k<<<5, 64, 0, stream>>>(batch, gstart);

    aggE_k<<<(NN + 15) / 16, 256, 0, stream>>>(eattr, rowstart, csr, aggE, NN);
    vninit_k<<<(NSHADOW * BB * HH) / 256, 256, 0, stream>>>(vn_init, vn, vn16, pooled8);
    xprep_k<<<(NN * 32 + 255) / 256, 256, 0, stream>>>(x, X0);

    wprep_k<<<(5 * 16384 + 255) / 256, 256, 0, stream>>>(node_W, WtN_h, WtN_l, 5 * 16384);
    wprep_k<<<(5 * 16384 + 255) / 256, 256, 0, stream>>>(mlp1_W, Wt1_h, Wt1_l, 5 * 16384);
    wprep_k<<<(5 * 16384 + 255) / 256, 256, 0, stream>>>(mlp2_W, Wt2_h, Wt2_l, 5 * 16384);

    const int GN = (NN + 63) / 64;
    const _Float16* xin = X0;
    for (int l = 0; l < LL; ++l) {
        // NOTE: l==0 uses usevn=0 — vn_init is identically zero per the problem spec,
        // so the VnSum term vanishes for the first layer.
        aggregate2_k<<<(NN + 15) / 16, 256, 0, stream>>>(xin, aggE,
            edge_W + (size_t)l * EDD * HH, edge_b + (size_t)l * HH, node_b + (size_t)l * HH,
            vn16, (l > 0) ? 1 : 0, rowstart, csr, AggX, Extra, NN);
        gemm_fused_k<<<GN, 256, 0, stream>>>(AggX, Extra,
            WtN_h + (size_t)l * 16384, WtN_l + (size_t)l * 16384,
            Wt1_h + (size_t)l * 16384, Wt1_l + (size_t)l * 16384, mlp1_b + (size_t)l * HH,
            Wt2_h + (size_t)l * 16384, Wt2_l + (size_t)l * 16384, mlp2_b + (size_t)l * HH,
            X, pooled8, batch, NN);
        if (l < LL - 1)
            vn_update_k<<<BB, 128, 0, stream>>>(pooled8, gstart, vn_w0, vn_b0, vn_w1, vn_b1, vn, vn16);
        xin = X;
    }
    fc_k<<<BB, 128, 0, stream>>>(pooled8, gstart, fc_W, fc_b, (float*)d_out);
}

// Round 2
// 607.916 us; speedup vs baseline: 1.0275x; 1.0275x over previous
//
#include <hip/hip_runtime.h>

#define NN 50000
#define EE 600000
#define HH 128
#define EDD 16
#define BB 256
#define LL 5
#define NN16 (NN * 16)
#define NSHADOW 8

typedef float f32x4 __attribute__((ext_vector_type(4)));
typedef _Float16 f16x4 __attribute__((ext_vector_type(4)));
typedef _Float16 f16x8 __attribute__((ext_vector_type(8)));

// ---------------- Weight prep: W[mat][k][n] fp32 -> frag-ordered fp16 hi/lo (K=128) ----------------
__global__ __launch_bounds__(256) void wprep_k(const float* __restrict__ W,
    _Float16* __restrict__ Wh, _Float16* __restrict__ Wl, int total)
{
    int idx = blockIdx.x * 256 + threadIdx.x;
    if (idx >= total) return;
    int mat = idx >> 14;
    int r = idx & 16383;
    int j = r & 7, lane = (r >> 3) & 63, ks = (r >> 9) & 3, ntw = (r >> 11) & 7;
    int lm = lane & 15, quad = lane >> 4;
    int n = (ntw >> 1) * 32 + (ntw & 1) * 16 + lm;
    int k = ks * 32 + quad * 8 + j;
    float w = W[(mat << 14) + (k << 7) + n];
    _Float16 h = (_Float16)w;
    Wh[idx] = h;
    Wl[idx] = (_Float16)(w - (float)h);
}

// ---------------- BX prep: per-layer [64 x 128] = [eW; eW; eb+nb; 0] -> frag fp16 hi/lo (K=64) ----------------
__global__ __launch_bounds__(256) void bext_k(const float* __restrict__ eW,
    const float* __restrict__ eb, const float* __restrict__ nb,
    _Float16* __restrict__ BXh, _Float16* __restrict__ BXl)
{
    int idx = blockIdx.x * 256 + threadIdx.x;
    if (idx >= 5 * 8192) return;
    int j = idx & 7, lane = (idx >> 3) & 63, ks = (idx >> 9) & 1, ntw = (idx >> 10) & 7, l = idx >> 13;
    int lm = lane & 15, quad = lane >> 4;
    int n = (ntw >> 1) * 32 + (ntw & 1) * 16 + lm;
    int k = ks * 32 + quad * 8 + j;
    float v = 0.f;
    if (k < 16) v = eW[((size_t)l * 16 + k) * 128 + n];          // hi part of aggE multiplies eW
    else if (k < 32) v = eW[((size_t)l * 16 + (k - 16)) * 128 + n]; // lo part multiplies eW too
    else if (k == 32) v = eb[l * 128 + n] + nb[l * 128 + n];     // deg column
    _Float16 h = (_Float16)v;
    BXh[idx] = h;
    BXl[idx] = (_Float16)(v - (float)h);
}

// ---------------- x -> fp16 (one-time) ----------------
__global__ __launch_bounds__(256) void xprep_k(const float* __restrict__ x,
    _Float16* __restrict__ X)
{
    int i = blockIdx.x * 256 + threadIdx.x;
    if (i >= NN * 32) return;
    float4 v = ((const float4*)x)[i];
    f16x4 o;
    o[0] = (_Float16)v.x; o[1] = (_Float16)v.y; o[2] = (_Float16)v.z; o[3] = (_Float16)v.w;
    ((f16x4*)X)[i] = o;
}

// ---------------- shared GEMM helpers ----------------
__device__ __forceinline__ void stage_A16(const _Float16* __restrict__ Ag, int M, int brow,
    int tid, _Float16* __restrict__ As)
{
    const int r = tid >> 2, cg = tid & 3;
    const int grow = brow + r;
    _Float16* p = As + r * 136 + cg * 32;
    if (grow < M) {
        const f16x8* s = (const f16x8*)(Ag + (size_t)grow * 128 + cg * 32);
#pragma unroll
        for (int i = 0; i < 4; ++i) ((f16x8*)p)[i] = s[i];
    } else {
        f16x8 z = (f16x8)(_Float16)0;
#pragma unroll
        for (int i = 0; i < 4; ++i) ((f16x8*)p)[i] = z;
    }
}

__device__ __forceinline__ void mfma_stage16(
    const _Float16* __restrict__ As,
    const _Float16* __restrict__ Wh, const _Float16* __restrict__ Wl,
    int wn, int lm, int quad, int lane, f32x4 acc[4][2])
{
    f16x8 Bh[2][4], Bl[2][4];
#pragma unroll
    for (int nt = 0; nt < 2; ++nt)
#pragma unroll
        for (int ks = 0; ks < 4; ++ks) {
            int fi = ((((wn * 2 + nt) * 4) + ks) * 64 + lane) * 8;
            Bh[nt][ks] = *(const f16x8*)(Wh + fi);
            Bl[nt][ks] = *(const f16x8*)(Wl + fi);
        }
#pragma unroll
    for (int ks = 0; ks < 4; ++ks) {
        f16x8 a[4];
#pragma unroll
        for (int mt = 0; mt < 4; ++mt) {
            int off = (mt * 16 + lm) * 136 + ks * 32 + quad * 8;
            a[mt] = *(const f16x8*)(As + off);
        }
#pragma unroll
        for (int mt = 0; mt < 4; ++mt)
#pragma unroll
            for (int nt = 0; nt < 2; ++nt) {
                acc[mt][nt] = __builtin_amdgcn_mfma_f32_16x16x32_f16(a[mt], Bh[nt][ks], acc[mt][nt], 0, 0, 0);
                acc[mt][nt] = __builtin_amdgcn_mfma_f32_16x16x32_f16(a[mt], Bl[nt][ks], acc[mt][nt], 0, 0, 0);
            }
    }
}

__device__ __forceinline__ void store_f16(const _Float16* __restrict__ Fo,
    _Float16* __restrict__ out, int M, int brow, int tid)
{
    const int r = tid >> 2, cg = tid & 3;
    const int grow = brow + r;
    if (grow >= M) return;
    const f16x8* src = (const f16x8*)(Fo + r * 136 + cg * 32);
    f16x8* dst = (f16x8*)(out + (size_t)grow * 128 + cg * 32);
#pragma unroll
    for (int i = 0; i < 4; ++i) dst[i] = src[i];
}

// ---------------- fused layer kernel: GEMM1(K=128 AggX + K=64 Afix + K=256 C@vn) -> MLP1 -> MLP2 ----------------
__global__ __launch_bounds__(256) void gemm_fused_k(
    const _Float16* __restrict__ AggX, const _Float16* __restrict__ Afix,
    const _Float16* __restrict__ Cfrag, const _Float16* __restrict__ vnB, int usevn,
    const _Float16* __restrict__ WNh, const _Float16* __restrict__ WNl,
    const _Float16* __restrict__ BXh, const _Float16* __restrict__ BXl,
    const _Float16* __restrict__ W1h, const _Float16* __restrict__ W1l, const float* __restrict__ b1,
    const _Float16* __restrict__ W2h, const _Float16* __restrict__ W2l, const float* __restrict__ b2,
    _Float16* __restrict__ X, float* __restrict__ pooled8,
    const int* __restrict__ batch, int M)
{
    __shared__ __align__(16) _Float16 bufA[64 * 136];
    __shared__ __align__(16) _Float16 bufB[64 * 136];   // first 64*72 doubles as Afix stage
    const int tid = threadIdx.x, brow = blockIdx.x * 64;

    stage_A16(AggX, M, brow, tid, bufA);
    {   // stage Afix [64 x 64] fp16 at stride 72
        const int r = tid >> 2, cg = tid & 3;
        const int grow = brow + r;
        _Float16* p = bufB + r * 72 + cg * 16;
        if (grow < M) {
            const f16x8* s = (const f16x8*)(Afix + (size_t)grow * 64 + cg * 16);
            ((f16x8*)p)[0] = s[0]; ((f16x8*)p)[1] = s[1];
        } else {
            f16x8 z = (f16x8)(_Float16)0;
            ((f16x8*)p)[0] = z; ((f16x8*)p)[1] = z;
        }
    }
    __syncthreads();

    const int lane = tid & 63, wn = tid >> 6, lm = lane & 15, quad = lane >> 4;
    const int colb = wn * 32 + lm;

    f32x4 acc[4][2];
#pragma unroll
    for (int mt = 0; mt < 4; ++mt) { acc[mt][0] = (f32x4)(0.f); acc[mt][1] = (f32x4)(0.f); }

    // K=128: AggX @ nW (hi/lo)
    mfma_stage16(bufA, WNh, WNl, wn, lm, quad, lane, acc);

    // K=64: [aggE_hi|aggE_lo|deg] @ [eW;eW;eb+nb] (B hi/lo)
#pragma unroll
    for (int ksf = 0; ksf < 2; ++ksf) {
        f16x8 Bh[2], Bl[2];
#pragma unroll
        for (int nt = 0; nt < 2; ++nt) {
            int fi = (((wn * 2 + nt) * 2 + ksf) * 64 + lane) * 8;
            Bh[nt] = *(const f16x8*)(BXh + fi);
            Bl[nt] = *(const f16x8*)(BXl + fi);
        }
#pragma unroll
        for (int mt = 0; mt < 4; ++mt) {
            f16x8 a = *(const f16x8*)(bufB + (mt * 16 + lm) * 72 + ksf * 32 + quad * 8);
#pragma unroll
            for (int nt = 0; nt < 2; ++nt) {
                acc[mt][nt] = __builtin_amdgcn_mfma_f32_16x16x32_f16(a, Bh[nt], acc[mt][nt], 0, 0, 0);
                acc[mt][nt] = __builtin_amdgcn_mfma_f32_16x16x32_f16(a, Bl[nt], acc[mt][nt], 0, 0, 0);
            }
        }
    }

    // K=256: C @ vn (counts exact in fp16; vn fp16 as before)
    if (usevn) {
        const _Float16* Cb = Cfrag + (size_t)blockIdx.x * 16384;
#pragma unroll
        for (int ks = 0; ks < 8; ++ks) {
            f16x8 bv[2];
#pragma unroll
            for (int nt = 0; nt < 2; ++nt)
                bv[nt] = *(const f16x8*)(vnB + (((ks * 8 + (wn * 2 + nt)) * 64 + lane) * 8));
#pragma unroll
            for (int mt = 0; mt < 4; ++mt) {
                f16x8 av = *(const f16x8*)(Cb + (((mt * 8 + ks) * 64 + lane) * 8));
                acc[mt][0] = __builtin_amdgcn_mfma_f32_16x16x32_f16(av, bv[0], acc[mt][0], 0, 0, 0);
                acc[mt][1] = __builtin_amdgcn_mfma_f32_16x16x32_f16(av, bv[1], acc[mt][1], 0, 0, 0);
            }
        }
    }
    __syncthreads();

    // epilogue 1 (no relu, all bias terms already in GEMM): agg -> bufA
#pragma unroll
    for (int mt = 0; mt < 4; ++mt) {
#pragma unroll
        for (int r = 0; r < 4; ++r) {
            int trow = mt * 16 + quad * 4 + r;
            bufA[trow * 136 + colb]      = (_Float16)acc[mt][0][r];
            bufA[trow * 136 + colb + 16] = (_Float16)acc[mt][1][r];
        }
    }
    __syncthreads();

#pragma unroll
    for (int mt = 0; mt < 4; ++mt) { acc[mt][0] = (f32x4)(0.f); acc[mt][1] = (f32x4)(0.f); }
    mfma_stage16(bufA, W1h, W1l, wn, lm, quad, lane, acc);
    {
        const float c0 = b1[colb], c1 = b1[colb + 16];
#pragma unroll
        for (int mt = 0; mt < 4; ++mt) {
#pragma unroll
            for (int r = 0; r < 4; ++r) {
                int trow = mt * 16 + quad * 4 + r;
                bufB[trow * 136 + colb]      = (_Float16)fmaxf(acc[mt][0][r] + c0, 0.f);
                bufB[trow * 136 + colb + 16] = (_Float16)fmaxf(acc[mt][1][r] + c1, 0.f);
            }
        }
    }
    __syncthreads();

#pragma unroll
    for (int mt = 0; mt < 4; ++mt) { acc[mt][0] = (f32x4)(0.f); acc[mt][1] = (f32x4)(0.f); }
    mfma_stage16(bufB, W2h, W2l, wn, lm, quad, lane, acc);
    {
        const float d0 = b2[colb], d1 = b2[colb + 16];
#pragma unroll
        for (int mt = 0; mt < 4; ++mt) {
#pragma unroll
            for (int r = 0; r < 4; ++r) {
                int trow = mt * 16 + quad * 4 + r;
                bufA[trow * 136 + colb]      = (_Float16)fmaxf(acc[mt][0][r] + d0, 0.f);
                bufA[trow * 136 + colb + 16] = (_Float16)fmaxf(acc[mt][1][r] + d1, 0.f);
            }
        }
    }
    __syncthreads();
    store_f16(bufA, X, M, brow, tid);

    // pooled partial sums into shadow copy (blockIdx&7) to cut atomic line-contention 8x
    {
        float* pooled = pooled8 + (size_t)(blockIdx.x & (NSHADOW - 1)) * (BB * HH);
        const int c = tid & 127, half = tid >> 7;
        const int row0 = half * 32;
        float sum = 0.f;
        int curg = -1;
        for (int r2 = 0; r2 < 32; ++r2) {
            int grow = brow + row0 + r2;
            if (grow >= M) break;
            int g = batch[grow];
            if (g != curg) {
                if (curg >= 0) atomicAdd(&pooled[curg * 128 + c], sum);
                curg = g; sum = 0.f;
            }
            sum += (float)bufA[(row0 + r2) * 136 + c];
        }
        if (curg >= 0) atomicAdd(&pooled[curg * 128 + c], sum);
    }
}

// ---------------- pure gather: AggX[n] = sum X[src] over in-edges ----------------
__global__ __launch_bounds__(256) void gather_k(
    const _Float16* __restrict__ X, const int* __restrict__ rowstart,
    const int* __restrict__ csrc, _Float16* __restrict__ AggX, int n)
{
    const int tid = threadIdx.x;
    const int lane = tid & 15;
    const int node = blockIdx.x * 16 + (tid >> 4);
    if (node >= n) return;
    const int s = rowstart[node], e = rowstart[node + 1];
    const f16x8* X8 = (const f16x8*)X;

    float ax[8];
#pragma unroll
    for (int k = 0; k < 8; ++k) ax[k] = 0.f;

    int p = s;
    for (; p + 4 <= e; p += 4) {
        int s0 = csrc[p], s1 = csrc[p + 1], s2 = csrc[p + 2], s3 = csrc[p + 3];
        f16x8 x0 = X8[(size_t)s0 * 16 + lane];
        f16x8 x1 = X8[(size_t)s1 * 16 + lane];
        f16x8 x2 = X8[(size_t)s2 * 16 + lane];
        f16x8 x3 = X8[(size_t)s3 * 16 + lane];
#pragma unroll
        for (int k = 0; k < 8; ++k)
            ax[k] += ((float)x0[k] + (float)x1[k]) + ((float)x2[k] + (float)x3[k]);
    }
    for (; p < e; ++p) {
        f16x8 x0 = X8[(size_t)csrc[p] * 16 + lane];
#pragma unroll
        for (int k = 0; k < 8; ++k) ax[k] += (float)x0[k];
    }

    f16x8 o;
#pragma unroll
    for (int k = 0; k < 8; ++k) o[k] = (_Float16)ax[k];
    ((f16x8*)AggX)[(size_t)node * 16 + lane] = o;
}

// ---------------- aggE via direct atomics from edge order (coalesced eattr reads) ----------------
__global__ __launch_bounds__(256) void aggEat_k(
    const float* __restrict__ eattr, const int* __restrict__ dstv,
    float* __restrict__ aggE)
{
    int i = blockIdx.x * 256 + threadIdx.x;
    if (i >= EE * 16) return;
    int e = i >> 4, k = i & 15;
    atomicAdd(&aggE[(size_t)dstv[e] * 16 + k], eattr[i]);
}

// ---------------- Afix[n][64] = [aggE_hi(16) | aggE_lo(16) | deg(1) | 0...] fp16 ----------------
__global__ __launch_bounds__(256) void afix_k(
    const float* __restrict__ aggE, const int* __restrict__ rowstart,
    _Float16* __restrict__ Afix, int n)
{
    const int tid = threadIdx.x;
    const int node = blockIdx.x * 64 + (tid >> 2);
    if (node >= n) return;
    const int cg = tid & 3;
    _Float16* dst = Afix + (size_t)node * 64 + cg * 16;
    f16x8 o0 = (f16x8)(_Float16)0, o1 = (f16x8)(_Float16)0;
    if (cg < 2) {
        const float* ae = aggE + (size_t)node * 16;
#pragma unroll
        for (int k = 0; k < 16; ++k) {
            float v = ae[k];
            _Float16 h = (_Float16)v;
            _Float16 out = (cg == 0) ? h : (_Float16)(v - (float)h);
            if (k < 8) o0[k] = out; else o1[k - 8] = out;
        }
    } else if (cg == 2) {
        o0[0] = (_Float16)(float)(rowstart[node + 1] - rowstart[node]);
    }
    ((f16x8*)dst)[0] = o0;
    ((f16x8*)dst)[1] = o1;
}

// ---------------- C counts: histogram + frag-ordered fp16 conversion ----------------
__global__ void histC_k(const int* __restrict__ dstv, const int* __restrict__ srcv,
                        const int* __restrict__ batch, int* __restrict__ Cint)
{
    int i = blockIdx.x * 256 + threadIdx.x;
    if (i < EE) atomicAdd(&Cint[(size_t)dstv[i] * 256 + batch[srcv[i]]], 1);
}

__global__ __launch_bounds__(256) void cfrag_k(const int* __restrict__ Cint,
                                               _Float16* __restrict__ Cfrag)
{
    const int brow = blockIdx.x * 64;
    const size_t base = (size_t)blockIdx.x * 16384;
    for (int e = threadIdx.x; e < 16384; e += 256) {
        int j = e & 7, lane = (e >> 3) & 63, ks = (e >> 9) & 7, mt = e >> 12;
        int row = brow + mt * 16 + (lane & 15);
        int g = ks * 32 + (lane >> 4) * 8 + j;
        _Float16 v = (_Float16)0;
        if (row < NN) v = (_Float16)(float)Cint[(size_t)row * 256 + g];
        Cfrag[base + e] = v;
    }
}

// ---------------- VN update from shadowed pooled sums (writes frag-ordered vnB) ----------------
__global__ __launch_bounds__(128) void vn_update_k(
    float* __restrict__ pooled8, const int* __restrict__ gstart,
    const float* __restrict__ W0, const float* __restrict__ b0,
    const float* __restrict__ W1, const float* __restrict__ b1,
    float* __restrict__ vn, _Float16* __restrict__ vnB)
{
    __shared__ float p[128], q[128];
    const int g = blockIdx.x, t = threadIdx.x;
    float cnt = (float)(gstart[g + 1] - gstart[g]);
    if (cnt < 1.f) cnt = 1.f;
    float sum = 0.f;
#pragma unroll
    for (int s = 0; s < NSHADOW; ++s) {
        float* slot = pooled8 + (size_t)s * (BB * HH) + g * 128 + t;
        sum += *slot;
        *slot = 0.f;
    }
    p[t] = sum / cnt;
    __syncthreads();
    float a0 = b0[t];
    for (int k = 0; k < 128; ++k) a0 = fmaf(p[k], W0[k * 128 + t], a0);
    q[t] = fmaxf(a0, 0.f);
    __syncthreads();
    float a1 = b1[t];
    for (int k = 0; k < 128; ++k) a1 = fmaf(q[k], W1[k * 128 + t], a1);
    float nv = vn[g * 128 + t] + fmaxf(a1, 0.f);
    vn[g * 128 + t] = nv;
    // frag-B position for the C@vn GEMM: k-index = g (graph), n-index = t (hidden col)
    {
        int ks = g >> 5, quad = (g >> 3) & 3, j = g & 7;
        int tt = ((t >> 5) << 1) | ((t >> 4) & 1);
        int lanev = quad * 16 + (t & 15);
        vnB[((ks * 8 + tt) * 64 + lanev) * 8 + j] = (_Float16)nv;
    }
}

// ---------------- final classifier from shadowed pooled sums ----------------
__global__ __launch_bounds__(128) void fc_k(
    const float* __restrict__ pooled8, const int* __restrict__ gstart,
    const float* __restrict__ W, const float* __restrict__ b,
    float* __restrict__ out)
{
    __shared__ float p[128];
    const int g = blockIdx.x, t = threadIdx.x;
    float cnt = (float)(gstart[g + 1] - gstart[g]);
    if (cnt < 1.f) cnt = 1.f;
    float sum = 0.f;
#pragma unroll
    for (int s = 0; s < NSHADOW; ++s)
        sum += pooled8[(size_t)s * (BB * HH) + g * 128 + t];
    p[t] = sum / cnt;
    __syncthreads();
    float acc = b[t];
    for (int k = 0; k < 128; ++k) acc = fmaf(p[k], W[k * 128 + t], acc);
    out[g * 128 + t] = acc;
}

// ---------------- CSR build helpers ----------------
__global__ void histp_k(const int* __restrict__ idx, int n, int* __restrict__ cntp)
{
    int i = blockIdx.x * 256 + threadIdx.x;
    if (i < n) atomicAdd(&cntp[(blockIdx.x & 3) * NN16 + (idx[i] << 4)], 1);
}

__global__ void scan_deg_k(const int* __restrict__ degp, int n, int* __restrict__ out, int* __restrict__ bsum)
{
    __shared__ int s[256];
    int gid = blockIdx.x * 256 + threadIdx.x;
    int v = 0;
    if (gid < n) {
        int o = gid << 4;
        v = degp[o] + degp[NN16 + o] + degp[2 * NN16 + o] + degp[3 * NN16 + o];
    }
    s[threadIdx.x] = v;
    __syncthreads();
    for (int off = 1; off < 256; off <<= 1) {
        int t = (threadIdx.x >= off) ? s[threadIdx.x - off] : 0;
        __syncthreads();
        s[threadIdx.x] += t;
        __syncthreads();
    }
    int incl = s[threadIdx.x];
    if (gid < n) out[gid] = incl - v;
    if (bsum != nullptr && threadIdx.x == 255) bsum[blockIdx.x] = incl;
}

__global__ void scan_k(const int* __restrict__ in, int n, int* __restrict__ out, int* __restrict__ bsum)
{
    __shared__ int s[256];
    int gid = blockIdx.x * 256 + threadIdx.x;
    int v = (gid < n) ? in[gid] : 0;
    s[threadIdx.x] = v;
    __syncthreads();
    for (int off = 1; off < 256; off <<= 1) {
        int t = (threadIdx.x >= off) ? s[threadIdx.x - off] : 0;
        __syncthreads();
        s[threadIdx.x] += t;
        __syncthreads();
    }
    int incl = s[threadIdx.x];
    if (gid < n) out[gid] = incl - v;
    if (bsum != nullptr && threadIdx.x == 255) bsum[blockIdx.x] = incl;
}

// addoff + cursor init fused
__global__ void addoff_k(int* __restrict__ data, const int* __restrict__ boff,
                         int* __restrict__ cursorp, int n, int total)
{
    int i = blockIdx.x * 256 + threadIdx.x;
    if (i < n) {
        int v = data[i] + boff[blockIdx.x];
        data[i] = v;
        cursorp[i << 4] = v;
    }
    if (i == 0) data[n] = total;
}

__global__ void fill_k(const int* __restrict__ dst, const int* __restrict__ src, int n,
                       int* __restrict__ cursorp, int* __restrict__ csrc)
{
    int e = blockIdx.x * 256 + threadIdx.x;
    if (e < n) {
        int slot = atomicAdd(&cursorp[dst[e] << 4], 1);
        csrc[slot] = src[e];
    }
}

__global__ void gstart_k(const int* __restrict__ batch, int* __restrict__ gstart)
{
    int b = blockIdx.x * 64 + threadIdx.x;
    if (b > BB) return;
    if (b == BB) { gstart[BB] = NN; return; }
    int lo = 0, hi = NN;
    while (lo < hi) {
        int mid = (lo + hi) >> 1;
        if (batch[mid] < b) lo = mid + 1; else hi = mid;
    }
    gstart[b] = lo;
}

__global__ void vninit_k(const float* __restrict__ vninit, float* __restrict__ vn,
                         _Float16* __restrict__ vnB, float* __restrict__ pooled8)
{
    int i = blockIdx.x * 256 + threadIdx.x;
    if (i < BB * HH) {
        vn[i] = vninit[i & 127];
        vnB[i] = (_Float16)0;   // vn_init is zeros per problem spec; layer 0 skips C@vn anyway
    }
    if (i < NSHADOW * BB * HH) pooled8[i] = 0.f;
}

// ---------------- Launch ----------------
extern "C" void kernel_launch(void* const* d_in, const int* in_sizes, int n_in,
                              void* d_out, int out_size, void* d_ws, size_t ws_size,
                              hipStream_t stream)
{
    (void)in_sizes; (void)n_in; (void)out_size; (void)ws_size;
    const float* x       = (const float*)d_in[0];
    const float* eattr   = (const float*)d_in[1];
    const float* node_W  = (const float*)d_in[2];
    const float* node_b  = (const float*)d_in[3];
    const float* edge_W  = (const float*)d_in[4];
    const float* edge_b  = (const float*)d_in[5];
    const float* mlp1_W  = (const float*)d_in[6];
    const float* mlp1_b  = (const float*)d_in[7];
    const float* mlp2_W  = (const float*)d_in[8];
    const float* mlp2_b  = (const float*)d_in[9];
    const float* vn_w0   = (const float*)d_in[10];
    const float* vn_b0   = (const float*)d_in[11];
    const float* vn_w1   = (const float*)d_in[12];
    const float* vn_b1   = (const float*)d_in[13];
    const float* fc_W    = (const float*)d_in[14];
    const float* fc_b    = (const float*)d_in[15];
    const float* vn_init = (const float*)d_in[16];
    const int*   eidx    = (const int*)d_in[17];
    const int*   batch   = (const int*)d_in[18];
    const int* srcv = eidx;
    const int* dstv = eidx + EE;

    char* wp = (char*)d_ws;
    auto alloc = [&](size_t bytes) -> void* {
        void* p = (void*)wp;
        wp += (bytes + 255) & ~(size_t)255;
        return p;
    };
    // zero-init region: degp | Cint | aggE contiguous (one memset)
    int* degp      = (int*)alloc((size_t)4 * NN16 * 4);            // 12.8 MB
    int* Cint      = (int*)alloc((size_t)NN * BB * 4);             // 51.2 MB
    float* aggE    = (float*)alloc((size_t)NN * EDD * 4);          // 3.2 MB
    const size_t zero_bytes = (size_t)4 * NN16 * 4 + (size_t)NN * BB * 4 + (size_t)NN * EDD * 4;

    _Float16* X0   = (_Float16*)alloc((size_t)NN * HH * 2);
    _Float16* X    = (_Float16*)alloc((size_t)NN * HH * 2);
    _Float16* AggX = (_Float16*)alloc((size_t)NN * HH * 2);
    _Float16* Afix = (_Float16*)alloc((size_t)NN * 64 * 2);
    _Float16* Cfrag= (_Float16*)alloc((size_t)782 * 16384 * 2);
    float* vn      = (float*)alloc((size_t)BB * HH * 4);
    _Float16* vnB  = (_Float16*)alloc((size_t)BB * HH * 2);
    float* pooled8 = (float*)alloc((size_t)NSHADOW * BB * HH * 4);
    int* rowstart  = (int*)alloc((size_t)(NN + 1) * 4);
    int* cursorp   = (int*)alloc((size_t)NN16 * 4);
    int* csrc      = (int*)alloc((size_t)EE * 4);
    int* bsum      = (int*)alloc(256 * 4);
    int* boff      = (int*)alloc(256 * 4);
    int* gstart    = (int*)alloc((size_t)(BB + 1) * 4);
    _Float16* WtN_h = (_Float16*)alloc((size_t)5 * 16384 * 2);
    _Float16* WtN_l = (_Float16*)alloc((size_t)5 * 16384 * 2);
    _Float16* Wt1_h = (_Float16*)alloc((size_t)5 * 16384 * 2);
    _Float16* Wt1_l = (_Float16*)alloc((size_t)5 * 16384 * 2);
    _Float16* Wt2_h = (_Float16*)alloc((size_t)5 * 16384 * 2);
    _Float16* Wt2_l = (_Float16*)alloc((size_t)5 * 16384 * 2);
    _Float16* BXh   = (_Float16*)alloc((size_t)5 * 8192 * 2);
    _Float16* BXl   = (_Float16*)alloc((size_t)5 * 8192 * 2);

    hipMemsetAsync(degp, 0, zero_bytes, stream);

    histp_k<<<(EE + 255) / 256, 256, 0, stream>>>(dstv, EE, degp);
    histC_k<<<(EE + 255) / 256, 256, 0, stream>>>(dstv, srcv, batch, Cint);
    aggEat_k<<<(EE * 16 + 255) / 256, 256, 0, stream>>>(eattr, dstv, aggE);

    const int NB1 = (NN + 255) / 256;
    scan_deg_k<<<NB1, 256, 0, stream>>>(degp, NN, rowstart, bsum);
    scan_k<<<1, 256, 0, stream>>>(bsum, NB1, boff, nullptr);
    addoff_k<<<NB1, 256, 0, stream>>>(rowstart, boff, cursorp, NN, EE);
    fill_k<<<(EE + 255) / 256, 256, 0, stream>>>(dstv, srcv, EE, cursorp, csrc);

    gstart_k<<<5, 64, 0, stream>>>(batch, gstart);

    afix_k<<<(NN + 63) / 64, 256, 0, stream>>>(aggE, rowstart, Afix, NN);
    cfrag_k<<<(NN + 63) / 64, 256, 0, stream>>>(Cint, Cfrag);
    vninit_k<<<(NSHADOW * BB * HH) / 256, 256, 0, stream>>>(vn_init, vn, vnB, pooled8);
    xprep_k<<<(NN * 32 + 255) / 256, 256, 0, stream>>>(x, X0);

    wprep_k<<<(5 * 16384 + 255) / 256, 256, 0, stream>>>(node_W, WtN_h, WtN_l, 5 * 16384);
    wprep_k<<<(5 * 16384 + 255) / 256, 256, 0, stream>>>(mlp1_W, Wt1_h, Wt1_l, 5 * 16384);
    wprep_k<<<(5 * 16384 + 255) / 256, 256, 0, stream>>>(mlp2_W, Wt2_h, Wt2_l, 5 * 16384);
    bext_k<<<(5 * 8192 + 255) / 256, 256, 0, stream>>>(edge_W, edge_b, node_b, BXh, BXl);

    const int GN = (NN + 63) / 64;
    const _Float16* xin = X0;
    for (int l = 0; l < LL; ++l) {
        gather_k<<<(NN + 15) / 16, 256, 0, stream>>>(xin, rowstart, csrc, AggX, NN);
        // l==0: vn is identically zero (vn_init zeros) -> skip C@vn; deg*(eb+nb) is in Afix path
        gemm_fused_k<<<GN, 256, 0, stream>>>(AggX, Afix, Cfrag, vnB, (l > 0) ? 1 : 0,
            WtN_h + (size_t)l * 16384, WtN_l + (size_t)l * 16384,
            BXh + (size_t)l * 8192, BXl + (size_t)l * 8192,
            Wt1_h + (size_t)l * 16384, Wt1_l + (size_t)l * 16384, mlp1_b + (size_t)l * HH,
            Wt2_h + (size_t)l * 16384, Wt2_l + (size_t)l * 16384, mlp2_b + (size_t)l * HH,
            X, pooled8, batch, NN);
        if (l < LL - 1)
            vn_update_k<<<BB, 128, 0, stream>>>(pooled8, gstart, vn_w0, vn_b0, vn_w1, vn_b1, vn, vnB);
        xin = X;
    }
    fc_k<<<BB, 128, 0, stream>>>(pooled8, gstart, fc_W, fc_b, (float*)d_out);
}

// Round 4
// 558.588 us; speedup vs baseline: 1.1183x; 1.0883x over previous
//
#include <hip/hip_runtime.h>

#define NN 50000
#define EE 600000
#define HH 128
#define EDD 16
#define BB 256
#define LL 5
#define NN16 (NN * 16)
#define NSHADOW 8
#define GN 782  // (NN+63)/64

typedef float f32x4 __attribute__((ext_vector_type(4)));
typedef _Float16 f16x4 __attribute__((ext_vector_type(4)));
typedef _Float16 f16x8 __attribute__((ext_vector_type(8)));

// ---------------- all weight prep in one kernel ----------------
// idx < 3*81920: W[mat][k][n] fp32 -> frag-ordered fp16 hi/lo (3 weight stacks)
// then 5*8192:  BX per-layer [64 x 128] = [eW; eW; eb+nb; 0] frag hi/lo (K=64)
__global__ __launch_bounds__(256) void wprep_all_k(
    const float* __restrict__ W0, const float* __restrict__ W1, const float* __restrict__ W2,
    _Float16* __restrict__ H0, _Float16* __restrict__ L0,
    _Float16* __restrict__ H1, _Float16* __restrict__ L1,
    _Float16* __restrict__ H2, _Float16* __restrict__ L2,
    const float* __restrict__ eW, const float* __restrict__ eb, const float* __restrict__ nb,
    _Float16* __restrict__ BXh, _Float16* __restrict__ BXl)
{
    int idx = blockIdx.x * 256 + threadIdx.x;
    if (idx < 3 * 81920) {
        int seg = idx / 81920, r = idx - seg * 81920;
        const float* W = (seg == 0) ? W0 : (seg == 1) ? W1 : W2;
        _Float16* Wh = (seg == 0) ? H0 : (seg == 1) ? H1 : H2;
        _Float16* Wl = (seg == 0) ? L0 : (seg == 1) ? L1 : L2;
        int mat = r >> 14;
        int rr = r & 16383;
        int j = rr & 7, lane = (rr >> 3) & 63, ks = (rr >> 9) & 3, ntw = (rr >> 11) & 7;
        int lm = lane & 15, quad = lane >> 4;
        int n = (ntw >> 1) * 32 + (ntw & 1) * 16 + lm;
        int k = ks * 32 + quad * 8 + j;
        float w = W[(mat << 14) + (k << 7) + n];
        _Float16 h = (_Float16)w;
        Wh[r] = h;
        Wl[r] = (_Float16)(w - (float)h);
    } else {
        int i2 = idx - 3 * 81920;
        if (i2 >= 5 * 8192) return;
        int j = i2 & 7, lane = (i2 >> 3) & 63, ks = (i2 >> 9) & 1, ntw = (i2 >> 10) & 7, l = i2 >> 13;
        int lm = lane & 15, quad = lane >> 4;
        int n = (ntw >> 1) * 32 + (ntw & 1) * 16 + lm;
        int k = ks * 32 + quad * 8 + j;
        float v = 0.f;
        if (k < 16) v = eW[((size_t)l * 16 + k) * 128 + n];
        else if (k < 32) v = eW[((size_t)l * 16 + (k - 16)) * 128 + n];
        else if (k == 32) v = eb[l * 128 + n] + nb[l * 128 + n];
        _Float16 h = (_Float16)v;
        BXh[i2] = h;
        BXl[i2] = (_Float16)(v - (float)h);
    }
}

// ---------------- misc one-time: x->fp16, vn init, vnB zero, pooled8 zero ----------------
__global__ __launch_bounds__(256) void misc_k(const float* __restrict__ x, _Float16* __restrict__ X0,
    const float* __restrict__ vninit, float* __restrict__ vn, _Float16* __restrict__ vnB,
    float* __restrict__ pooled8)
{
    int i = blockIdx.x * 256 + threadIdx.x;
    if (i < NN * 32) {
        float4 v = ((const float4*)x)[i];
        f16x4 o;
        o[0] = (_Float16)v.x; o[1] = (_Float16)v.y; o[2] = (_Float16)v.z; o[3] = (_Float16)v.w;
        ((f16x4*)X0)[i] = o;
    } else {
        int k = i - NN * 32;
        if (k < NSHADOW * BB * HH) pooled8[k] = 0.f;
        if (k < BB * HH) { vn[k] = vninit[k & 127]; vnB[k] = (_Float16)0; }
    }
}

// ---------------- shared GEMM helpers ----------------
__device__ __forceinline__ void mfma_stage16(
    const _Float16* __restrict__ As,
    const _Float16* __restrict__ Wh, const _Float16* __restrict__ Wl,
    int wn, int lm, int quad, int lane, f32x4 acc[4][2])
{
    f16x8 Bh[2][4], Bl[2][4];
#pragma unroll
    for (int nt = 0; nt < 2; ++nt)
#pragma unroll
        for (int ks = 0; ks < 4; ++ks) {
            int fi = ((((wn * 2 + nt) * 4) + ks) * 64 + lane) * 8;
            Bh[nt][ks] = *(const f16x8*)(Wh + fi);
            Bl[nt][ks] = *(const f16x8*)(Wl + fi);
        }
#pragma unroll
    for (int ks = 0; ks < 4; ++ks) {
        f16x8 a[4];
#pragma unroll
        for (int mt = 0; mt < 4; ++mt) {
            int off = (mt * 16 + lm) * 136 + ks * 32 + quad * 8;
            a[mt] = *(const f16x8*)(As + off);
        }
#pragma unroll
        for (int mt = 0; mt < 4; ++mt)
#pragma unroll
            for (int nt = 0; nt < 2; ++nt) {
                acc[mt][nt] = __builtin_amdgcn_mfma_f32_16x16x32_f16(a[mt], Bh[nt][ks], acc[mt][nt], 0, 0, 0);
                acc[mt][nt] = __builtin_amdgcn_mfma_f32_16x16x32_f16(a[mt], Bl[nt][ks], acc[mt][nt], 0, 0, 0);
            }
    }
}

__device__ __forceinline__ void store_f16(const _Float16* __restrict__ Fo,
    _Float16* __restrict__ out, int M, int brow, int tid)
{
    const int r = tid >> 2, cg = tid & 3;
    const int grow = brow + r;
    if (grow >= M) return;
    const f16x8* src = (const f16x8*)(Fo + r * 136 + cg * 32);
    f16x8* dst = (f16x8*)(out + (size_t)grow * 128 + cg * 32);
#pragma unroll
    for (int i = 0; i < 4; ++i) dst[i] = src[i];
}

// ---------------- fused layer kernel: gather + GEMM1(K=128 + K=64 Afix + K=256 C@vn) + MLP1 + MLP2 + pool ----------------
__global__ __launch_bounds__(256) void layer_k(
    const _Float16* __restrict__ Xin,
    const _Float16* __restrict__ Afix,
    const _Float16* __restrict__ Cfrag, const _Float16* __restrict__ vnB, int usevn,
    const int* __restrict__ rowstart, const int2* __restrict__ csr,
    const _Float16* __restrict__ WNh, const _Float16* __restrict__ WNl,
    const _Float16* __restrict__ BXh, const _Float16* __restrict__ BXl,
    const _Float16* __restrict__ W1h, const _Float16* __restrict__ W1l, const float* __restrict__ b1,
    const _Float16* __restrict__ W2h, const _Float16* __restrict__ W2l, const float* __restrict__ b2,
    _Float16* __restrict__ Xout, float* __restrict__ pooled8,
    const int* __restrict__ batch, int M)
{
    __shared__ __align__(16) _Float16 bufA[64 * 136];
    __shared__ __align__(16) _Float16 bufB[64 * 136];   // first 64*72 doubles as Afix stage
    const int tid = threadIdx.x, brow = blockIdx.x * 64;

    // stage Afix [64 x 64] fp16 at stride 72 into bufB
    {
        const int r = tid >> 2, cg = tid & 3;
        const int grow = brow + r;
        _Float16* p = bufB + r * 72 + cg * 16;
        if (grow < M) {
            const f16x8* s = (const f16x8*)(Afix + (size_t)grow * 64 + cg * 16);
            ((f16x8*)p)[0] = s[0]; ((f16x8*)p)[1] = s[1];
        } else {
            f16x8 z = (f16x8)(_Float16)0;
            ((f16x8*)p)[0] = z; ((f16x8*)p)[1] = z;
        }
    }

    // gather phase: bufA[node] = fp16( sum_{e: dst=node} Xin[src_e] )  (fp32 accum)
    {
        const int wv = tid >> 6, grp = (tid >> 4) & 3, li = tid & 15;
        const f16x8* X8 = (const f16x8*)Xin;
        for (int j = 0; j < 4; ++j) {
            int rnode = wv * 16 + grp * 4 + j;
            int node = brow + rnode;
            f16x8 o = (f16x8)(_Float16)0;
            if (node < M) {
                int s = rowstart[node], e = rowstart[node + 1];
                float ax[8];
#pragma unroll
                for (int k = 0; k < 8; ++k) ax[k] = 0.f;
                int p = s;
                for (; p + 4 <= e; p += 4) {
                    int s0 = csr[p].x, s1 = csr[p + 1].x, s2 = csr[p + 2].x, s3 = csr[p + 3].x;
                    f16x8 x0 = X8[(size_t)s0 * 16 + li];
                    f16x8 x1 = X8[(size_t)s1 * 16 + li];
                    f16x8 x2 = X8[(size_t)s2 * 16 + li];
                    f16x8 x3 = X8[(size_t)s3 * 16 + li];
#pragma unroll
                    for (int k = 0; k < 8; ++k)
                        ax[k] += ((float)x0[k] + (float)x1[k]) + ((float)x2[k] + (float)x3[k]);
                }
                for (; p < e; ++p) {
                    f16x8 x0 = X8[(size_t)csr[p].x * 16 + li];
#pragma unroll
                    for (int k = 0; k < 8; ++k) ax[k] += (float)x0[k];
                }
#pragma unroll
                for (int k = 0; k < 8; ++k) o[k] = (_Float16)ax[k];
            }
            *(f16x8*)(bufA + rnode * 136 + li * 8) = o;
        }
    }
    __syncthreads();

    const int lane = tid & 63, wn = tid >> 6, lm = lane & 15, quad = lane >> 4;
    const int colb = wn * 32 + lm;

    f32x4 acc[4][2];
#pragma unroll
    for (int mt = 0; mt < 4; ++mt) { acc[mt][0] = (f32x4)(0.f); acc[mt][1] = (f32x4)(0.f); }

    // K=128: AggX @ nW (hi/lo)
    mfma_stage16(bufA, WNh, WNl, wn, lm, quad, lane, acc);

    // K=64: [aggE_hi|aggE_lo|deg] @ [eW;eW;eb+nb] (B hi/lo)
#pragma unroll
    for (int ksf = 0; ksf < 2; ++ksf) {
        f16x8 Bh[2], Bl[2];
#pragma unroll
        for (int nt = 0; nt < 2; ++nt) {
            int fi = (((wn * 2 + nt) * 2 + ksf) * 64 + lane) * 8;
            Bh[nt] = *(const f16x8*)(BXh + fi);
            Bl[nt] = *(const f16x8*)(BXl + fi);
        }
#pragma unroll
        for (int mt = 0; mt < 4; ++mt) {
            f16x8 a = *(const f16x8*)(bufB + (mt * 16 + lm) * 72 + ksf * 32 + quad * 8);
#pragma unroll
            for (int nt = 0; nt < 2; ++nt) {
                acc[mt][nt] = __builtin_amdgcn_mfma_f32_16x16x32_f16(a, Bh[nt], acc[mt][nt], 0, 0, 0);
                acc[mt][nt] = __builtin_amdgcn_mfma_f32_16x16x32_f16(a, Bl[nt], acc[mt][nt], 0, 0, 0);
            }
        }
    }

    // K=256: C @ vn (counts exact fp16)
    if (usevn) {
        const _Float16* Cb = Cfrag + (size_t)blockIdx.x * 16384;
#pragma unroll
        for (int ks = 0; ks < 8; ++ks) {
            f16x8 bv[2];
#pragma unroll
            for (int nt = 0; nt < 2; ++nt)
                bv[nt] = *(const f16x8*)(vnB + (((ks * 8 + (wn * 2 + nt)) * 64 + lane) * 8));
#pragma unroll
            for (int mt = 0; mt < 4; ++mt) {
                f16x8 av = *(const f16x8*)(Cb + (((mt * 8 + ks) * 64 + lane) * 8));
                acc[mt][0] = __builtin_amdgcn_mfma_f32_16x16x32_f16(av, bv[0], acc[mt][0], 0, 0, 0);
                acc[mt][1] = __builtin_amdgcn_mfma_f32_16x16x32_f16(av, bv[1], acc[mt][1], 0, 0, 0);
            }
        }
    }
    __syncthreads();

    // epilogue 1 (no relu; all bias terms already inside GEMM): agg -> bufA
#pragma unroll
    for (int mt = 0; mt < 4; ++mt) {
#pragma unroll
        for (int r = 0; r < 4; ++r) {
            int trow = mt * 16 + quad * 4 + r;
            bufA[trow * 136 + colb]      = (_Float16)acc[mt][0][r];
            bufA[trow * 136 + colb + 16] = (_Float16)acc[mt][1][r];
        }
    }
    __syncthreads();

#pragma unroll
    for (int mt = 0; mt < 4; ++mt) { acc[mt][0] = (f32x4)(0.f); acc[mt][1] = (f32x4)(0.f); }
    mfma_stage16(bufA, W1h, W1l, wn, lm, quad, lane, acc);
    {
        const float c0 = b1[colb], c1 = b1[colb + 16];
#pragma unroll
        for (int mt = 0; mt < 4; ++mt) {
#pragma unroll
            for (int r = 0; r < 4; ++r) {
                int trow = mt * 16 + quad * 4 + r;
                bufB[trow * 136 + colb]      = (_Float16)fmaxf(acc[mt][0][r] + c0, 0.f);
                bufB[trow * 136 + colb + 16] = (_Float16)fmaxf(acc[mt][1][r] + c1, 0.f);
            }
        }
    }
    __syncthreads();

#pragma unroll
    for (int mt = 0; mt < 4; ++mt) { acc[mt][0] = (f32x4)(0.f); acc[mt][1] = (f32x4)(0.f); }
    mfma_stage16(bufB, W2h, W2l, wn, lm, quad, lane, acc);
    {
        const float d0 = b2[colb], d1 = b2[colb + 16];
#pragma unroll
        for (int mt = 0; mt < 4; ++mt) {
#pragma unroll
            for (int r = 0; r < 4; ++r) {
                int trow = mt * 16 + quad * 4 + r;
                bufA[trow * 136 + colb]      = (_Float16)fmaxf(acc[mt][0][r] + d0, 0.f);
                bufA[trow * 136 + colb + 16] = (_Float16)fmaxf(acc[mt][1][r] + d1, 0.f);
            }
        }
    }
    __syncthreads();
    store_f16(bufA, Xout, M, brow, tid);

    // pooled partial sums into shadow copy (blockIdx&7)
    {
        float* pooled = pooled8 + (size_t)(blockIdx.x & (NSHADOW - 1)) * (BB * HH);
        const int c = tid & 127, half = tid >> 7;
        const int row0 = half * 32;
        float sum = 0.f;
        int curg = -1;
        for (int r2 = 0; r2 < 32; ++r2) {
            int grow = brow + row0 + r2;
            if (grow >= M) break;
            int g = batch[grow];
            if (g != curg) {
                if (curg >= 0) atomicAdd(&pooled[curg * 128 + c], sum);
                curg = g; sum = 0.f;
            }
            sum += (float)bufA[(row0 + r2) * 136 + c];
        }
        if (curg >= 0) atomicAdd(&pooled[curg * 128 + c], sum);
    }
}

// ---------------- aggE + Afix merged: per-node eattr sum -> [hi|lo|deg|0] fp16 ----------------
__global__ __launch_bounds__(256) void aggfix_k(
    const float* __restrict__ eattr, const int* __restrict__ rowstart,
    const int2* __restrict__ csr, _Float16* __restrict__ Afix, int n)
{
    const int lane = threadIdx.x & 15;
    const int node = blockIdx.x * 16 + (threadIdx.x >> 4);
    if (node >= n) return;
    const int s = rowstart[node], e = rowstart[node + 1];
    float acc = 0.f;
    for (int p = s; p < e; ++p)
        acc += eattr[(size_t)csr[p].y * 16 + lane];
    _Float16 hi = (_Float16)acc;
    _Float16 lo = (_Float16)(acc - (float)hi);
    _Float16* A = Afix + (size_t)node * 64;
    A[lane] = hi;
    A[16 + lane] = lo;
    A[32 + lane] = (lane == 0) ? (_Float16)(float)(e - s) : (_Float16)0;
    A[48 + lane] = (_Float16)0;
}

// ---------------- histogram (deg) + packed u16 Cfrag counts via u32 atomics ----------------
// counts per (node,graph) are tiny (<< 65536) so the two 16-bit halves never carry.
__global__ void histboth_k(const int* __restrict__ dstv, const int* __restrict__ srcv,
                           const int* __restrict__ batch,
                           int* __restrict__ degp, unsigned int* __restrict__ Cpack)
{
    int i = blockIdx.x * 256 + threadIdx.x;
    if (i >= EE) return;
    int d = dstv[i];
    atomicAdd(&degp[(blockIdx.x & 3) * NN16 + (d << 4)], 1);
    int g = batch[srcv[i]];
    int blk = d >> 6, rib = d & 63, mt = rib >> 4, lm = rib & 15;
    int ks = g >> 5, quad = (g >> 3) & 3, j = g & 7;
    size_t e = (size_t)blk * 16384 + (size_t)(((mt * 8 + ks) * 64) + quad * 16 + lm) * 8 + j;
    atomicAdd(&Cpack[e >> 1], 1u << ((e & 1) * 16));
}

// ---------------- in-place convert packed u16 counts -> fp16 ----------------
__global__ __launch_bounds__(256) void ccvt_k(unsigned int* __restrict__ Cpack)
{
    int i = blockIdx.x * 256 + threadIdx.x;
    if (i >= GN * 16384 / 2) return;
    unsigned int v = Cpack[i];
    _Float16 lo = (_Float16)(float)(v & 0xffffu);
    _Float16 hi = (_Float16)(float)(v >> 16);
    unsigned short lu = __builtin_bit_cast(unsigned short, lo);
    unsigned short hu = __builtin_bit_cast(unsigned short, hi);
    Cpack[i] = (unsigned int)lu | ((unsigned int)hu << 16);
}

// ---------------- VN update (writes frag-ordered vnB) ----------------
__global__ __launch_bounds__(128) void vn_update_k(
    float* __restrict__ pooled8, const int* __restrict__ gstart,
    const float* __restrict__ W0, const float* __restrict__ b0,
    const float* __restrict__ W1, const float* __restrict__ b1,
    float* __restrict__ vn, _Float16* __restrict__ vnB)
{
    __shared__ float p[128], q[128];
    const int g = blockIdx.x, t = threadIdx.x;
    float cnt = (float)(gstart[g + 1] - gstart[g]);
    if (cnt < 1.f) cnt = 1.f;
    float sum = 0.f;
#pragma unroll
    for (int s = 0; s < NSHADOW; ++s) {
        float* slot = pooled8 + (size_t)s * (BB * HH) + g * 128 + t;
        sum += *slot;
        *slot = 0.f;
    }
    p[t] = sum / cnt;
    __syncthreads();
    float a0 = b0[t];
    for (int k = 0; k < 128; ++k) a0 = fmaf(p[k], W0[k * 128 + t], a0);
    q[t] = fmaxf(a0, 0.f);
    __syncthreads();
    float a1 = b1[t];
    for (int k = 0; k < 128; ++k) a1 = fmaf(q[k], W1[k * 128 + t], a1);
    float nv = vn[g * 128 + t] + fmaxf(a1, 0.f);
    vn[g * 128 + t] = nv;
    {
        int ks = g >> 5, quad = (g >> 3) & 3, j = g & 7;
        int tt = ((t >> 5) << 1) | ((t >> 4) & 1);
        int lanev = quad * 16 + (t & 15);
        vnB[((ks * 8 + tt) * 64 + lanev) * 8 + j] = (_Float16)nv;
    }
}

// ---------------- final classifier ----------------
__global__ __launch_bounds__(128) void fc_k(
    const float* __restrict__ pooled8, const int* __restrict__ gstart,
    const float* __restrict__ W, const float* __restrict__ b,
    float* __restrict__ out)
{
    __shared__ float p[128];
    const int g = blockIdx.x, t = threadIdx.x;
    float cnt = (float)(gstart[g + 1] - gstart[g]);
    if (cnt < 1.f) cnt = 1.f;
    float sum = 0.f;
#pragma unroll
    for (int s = 0; s < NSHADOW; ++s)
        sum += pooled8[(size_t)s * (BB * HH) + g * 128 + t];
    p[t] = sum / cnt;
    __syncthreads();
    float acc = b[t];
    for (int k = 0; k < 128; ++k) acc = fmaf(p[k], W[k * 128 + t], acc);
    out[g * 128 + t] = acc;
}

// ---------------- CSR build ----------------
__global__ void scan_deg_k(const int* __restrict__ degp, int n, int* __restrict__ out, int* __restrict__ bsum)
{
    __shared__ int s[256];
    int gid = blockIdx.x * 256 + threadIdx.x;
    int v = 0;
    if (gid < n) {
        int o = gid << 4;
        v = degp[o] + degp[NN16 + o] + degp[2 * NN16 + o] + degp[3 * NN16 + o];
    }
    s[threadIdx.x] = v;
    __syncthreads();
    for (int off = 1; off < 256; off <<= 1) {
        int t = (threadIdx.x >= off) ? s[threadIdx.x - off] : 0;
        __syncthreads();
        s[threadIdx.x] += t;
        __syncthreads();
    }
    int incl = s[threadIdx.x];
    if (gid < n) out[gid] = incl - v;
    if (bsum != nullptr && threadIdx.x == 255) bsum[blockIdx.x] = incl;
}

// block-sums scan + gstart (single block)
__global__ void scan_k(const int* __restrict__ in, int n, int* __restrict__ out,
                       const int* __restrict__ batch, int* __restrict__ gstart)
{
    __shared__ int s[256];
    int v = (threadIdx.x < n) ? in[threadIdx.x] : 0;
    s[threadIdx.x] = v;
    __syncthreads();
    for (int off = 1; off < 256; off <<= 1) {
        int t = (threadIdx.x >= off) ? s[threadIdx.x - off] : 0;
        __syncthreads();
        s[threadIdx.x] += t;
        __syncthreads();
    }
    if (threadIdx.x < n) out[threadIdx.x] = s[threadIdx.x] - v;
    // gstart fold: one binary search per graph
    {
        int b = threadIdx.x;
        int lo = 0, hi = NN;
        while (lo < hi) {
            int mid = (lo + hi) >> 1;
            if (batch[mid] < b) lo = mid + 1; else hi = mid;
        }
        gstart[b] = lo;
        if (threadIdx.x == 0) gstart[BB] = NN;
    }
}

__global__ void addoff_k(int* __restrict__ data, const int* __restrict__ boff,
                         int* __restrict__ cursorp, int n, int total)
{
    int i = blockIdx.x * 256 + threadIdx.x;
    if (i < n) {
        int v = data[i] + boff[blockIdx.x];
        data[i] = v;
        cursorp[i << 4] = v;
    }
    if (i == 0) data[n] = total;
}

__global__ void fill_k(const int* __restrict__ dst, const int* __restrict__ src, int n,
                       int* __restrict__ cursorp, int2* __restrict__ csr)
{
    int e = blockIdx.x * 256 + threadIdx.x;
    if (e < n) {
        int slot = atomicAdd(&cursorp[dst[e] << 4], 1);
        int2 pr; pr.x = src[e]; pr.y = e;
        csr[slot] = pr;
    }
}

// ---------------- Launch ----------------
extern "C" void kernel_launch(void* const* d_in, const int* in_sizes, int n_in,
                              void* d_out, int out_size, void* d_ws, size_t ws_size,
                              hipStream_t stream)
{
    (void)in_sizes; (void)n_in; (void)out_size; (void)ws_size;
    const float* x       = (const float*)d_in[0];
    const float* eattr   = (const float*)d_in[1];
    const float* node_W  = (const float*)d_in[2];
    const float* node_b  = (const float*)d_in[3];
    const float* edge_W  = (const float*)d_in[4];
    const float* edge_b  = (const float*)d_in[5];
    const float* mlp1_W  = (const float*)d_in[6];
    const float* mlp1_b  = (const float*)d_in[7];
    const float* mlp2_W  = (const float*)d_in[8];
    const float* mlp2_b  = (const float*)d_in[9];
    const float* vn_w0   = (const float*)d_in[10];
    const float* vn_b0   = (const float*)d_in[11];
    const float* vn_w1   = (const float*)d_in[12];
    const float* vn_b1   = (const float*)d_in[13];
    const float* fc_W    = (const float*)d_in[14];
    const float* fc_b    = (const float*)d_in[15];
    const float* vn_init = (const float*)d_in[16];
    const int*   eidx    = (const int*)d_in[17];
    const int*   batch   = (const int*)d_in[18];
    const int* srcv = eidx;
    const int* dstv = eidx + EE;

    char* wp = (char*)d_ws;
    auto alloc = [&](size_t bytes) -> void* {
        void* p = (void*)wp;
        wp += (bytes + 255) & ~(size_t)255;
        return p;
    };
    // zero-init region: degp | Cfrag contiguous (one memset)
    int* degp       = (int*)alloc((size_t)4 * NN16 * 4);             // 12.8 MB
    _Float16* Cfrag = (_Float16*)alloc((size_t)GN * 16384 * 2);      // 25.6 MB
    const size_t zero_bytes = (size_t)4 * NN16 * 4 + (size_t)GN * 16384 * 2;

    _Float16* X0   = (_Float16*)alloc((size_t)NN * HH * 2);
    _Float16* X1   = (_Float16*)alloc((size_t)NN * HH * 2);
    _Float16* X2   = (_Float16*)alloc((size_t)NN * HH * 2);
    _Float16* Afix = (_Float16*)alloc((size_t)NN * 64 * 2);
    float* vn      = (float*)alloc((size_t)BB * HH * 4);
    _Float16* vnB  = (_Float16*)alloc((size_t)BB * HH * 2);
    float* pooled8 = (float*)alloc((size_t)NSHADOW * BB * HH * 4);
    int* rowstart  = (int*)alloc((size_t)(NN + 1) * 4);
    int* cursorp   = (int*)alloc((size_t)NN16 * 4);
    int2* csr      = (int2*)alloc((size_t)EE * 8);
    int* bsum      = (int*)alloc(256 * 4);
    int* boff      = (int*)alloc(256 * 4);
    int* gstart    = (int*)alloc((size_t)(BB + 1) * 4);
    _Float16* WtN_h = (_Float16*)alloc((size_t)5 * 16384 * 2);
    _Float16* WtN_l = (_Float16*)alloc((size_t)5 * 16384 * 2);
    _Float16* Wt1_h = (_Float16*)alloc((size_t)5 * 16384 * 2);
    _Float16* Wt1_l = (_Float16*)alloc((size_t)5 * 16384 * 2);
    _Float16* Wt2_h = (_Float16*)alloc((size_t)5 * 16384 * 2);
    _Float16* Wt2_l = (_Float16*)alloc((size_t)5 * 16384 * 2);
    _Float16* BXh   = (_Float16*)alloc((size_t)5 * 8192 * 2);
    _Float16* BXl   = (_Float16*)alloc((size_t)5 * 8192 * 2);

    (void)hipMemsetAsync(degp, 0, zero_bytes, stream);

    histboth_k<<<(EE + 255) / 256, 256, 0, stream>>>(dstv, srcv, batch, degp, (unsigned int*)Cfrag);

    const int NB1 = (NN + 255) / 256;
    scan_deg_k<<<NB1, 256, 0, stream>>>(degp, NN, rowstart, bsum);
    scan_k<<<1, 256, 0, stream>>>(bsum, NB1, boff, batch, gstart);
    addoff_k<<<NB1, 256, 0, stream>>>(rowstart, boff, cursorp, NN, EE);
    fill_k<<<(EE + 255) / 256, 256, 0, stream>>>(dstv, srcv, EE, cursorp, csr);
    aggfix_k<<<(NN + 15) / 16, 256, 0, stream>>>(eattr, rowstart, csr, Afix, NN);
    ccvt_k<<<(GN * 16384 / 2 + 255) / 256, 256, 0, stream>>>((unsigned int*)Cfrag);

    misc_k<<<(NN * 32 + NSHADOW * BB * HH) / 256, 256, 0, stream>>>(x, X0, vn_init, vn, vnB, pooled8);
    wprep_all_k<<<(3 * 81920 + 5 * 8192) / 256, 256, 0, stream>>>(
        node_W, mlp1_W, mlp2_W, WtN_h, WtN_l, Wt1_h, Wt1_l, Wt2_h, Wt2_l,
        edge_W, edge_b, node_b, BXh, BXl);

    const _Float16* xin = X0;
    for (int l = 0; l < LL; ++l) {
        _Float16* xout = (l & 1) ? X2 : X1;
        layer_k<<<GN, 256, 0, stream>>>(xin, Afix, Cfrag, vnB, (l > 0) ? 1 : 0,
            rowstart, csr,
            WtN_h + (size_t)l * 16384, WtN_l + (size_t)l * 16384,
            BXh + (size_t)l * 8192, BXl + (size_t)l * 8192,
            Wt1_h + (size_t)l * 16384, Wt1_l + (size_t)l * 16384, mlp1_b + (size_t)l * HH,
            Wt2_h + (size_t)l * 16384, Wt2_l + (size_t)l * 16384, mlp2_b + (size_t)l * HH,
            xout, pooled8, batch, NN);
        if (l < LL - 1)
            vn_update_k<<<BB, 128, 0, stream>>>(pooled8, gstart, vn_w0, vn_b0, vn_w1, vn_b1, vn, vnB);
        xin = xout;
    }
    fc_k<<<BB, 128, 0, stream>>>(pooled8, gstart, fc_W, fc_b, (float*)d_out);
}